// Round 1
// baseline (231.092 us; speedup 1.0000x reference)
//
#include <hip/hip_runtime.h>
#include <stdint.h>
#include <math.h>

#define B_SZ   2048
#define D_SZ   128
#define C_SZ   100000
#define S_SC   30.0f
#define SM_    9.0f      // S*M = 30*0.3
#define EPS_   0.1f

// GEMM tiling
#define BM     128
#define BN     128
#define NSUB   8
#define CPB    (BN*NSUB)                  // 1024 cols per block
#define GRID_C ((C_SZ + CPB - 1)/CPB)     // 98
#define NSLOT  (GRID_C*2)                 // 196 partial slots per row (2 col-wave halves)

typedef float  f32x4  __attribute__((ext_vector_type(4)));
typedef short  bf16x8 __attribute__((ext_vector_type(8)));
typedef unsigned short u16;

__device__ __forceinline__ void gload_lds16(const void* g, void* l) {
  __builtin_amdgcn_global_load_lds(
      (const __attribute__((address_space(1))) void*)g,
      (__attribute__((address_space(3))) void*)l, 16, 0, 0);
}

__device__ __forceinline__ u16 f2bf(float f) {
  unsigned u = __float_as_uint(f);
  u += 0x7fffu + ((u >> 16) & 1u);   // round-to-nearest-even
  return (u16)(u >> 16);
}

// ---------------- row L2-normalize -> bf16 (one wave per row) ----------------
__global__ void rownorm_bf16_kernel(const float* __restrict__ in,
                                    u16* __restrict__ out, int rows) {
  int row  = (blockIdx.x * blockDim.x + threadIdx.x) >> 6;
  int lane = threadIdx.x & 63;
  if (row >= rows) return;
  float2 v = ((const float2*)(in + (size_t)row * D_SZ))[lane];
  float ss = v.x * v.x + v.y * v.y;
  #pragma unroll
  for (int m = 1; m < 64; m <<= 1) ss += __shfl_xor(ss, m, 64);
  float rn = 1.0f / sqrtf(ss);
  ushort2 o;
  o.x = f2bf(v.x * rn);
  o.y = f2bf(v.y * rn);
  ((ushort2*)(out + (size_t)row * D_SZ))[lane] = o;
}

// ---------------- exact fp32 cos at the label position ----------------
__global__ void labeldot_kernel(const float* __restrict__ f,
                                const int* __restrict__ labels,
                                const float* __restrict__ w,
                                float* __restrict__ cosy) {
  int row  = (blockIdx.x * blockDim.x + threadIdx.x) >> 6;
  int lane = threadIdx.x & 63;
  if (row >= B_SZ) return;
  int y = labels[row];
  float2 fv = ((const float2*)(f + (size_t)row * D_SZ))[lane];
  float2 wv = ((const float2*)(w + (size_t)y   * D_SZ))[lane];
  float d  = fv.x * wv.x + fv.y * wv.y;
  float ff = fv.x * fv.x + fv.y * fv.y;
  float ww = wv.x * wv.x + wv.y * wv.y;
  #pragma unroll
  for (int m = 1; m < 64; m <<= 1) {
    d  += __shfl_xor(d,  m, 64);
    ff += __shfl_xor(ff, m, 64);
    ww += __shfl_xor(ww, m, 64);
  }
  if (lane == 0) {
    float c = d / (sqrtf(ff) * sqrtf(ww));
    c = fminf(1.0f, fmaxf(-1.0f, c));
    cosy[row] = c;
  }
}

// ---------------- fused bf16 MFMA GEMM + softmax partials ----------------
// block: 256 thr (4 waves, 2x2). Per block: rows rt*128..+127, cols cb*1024..+1023.
// Partials per row per block-half: s = sum exp(z-30), u = sum z  (margin included).
__global__ __launch_bounds__(256, 2) void gemm_partial_kernel(
    const u16* __restrict__ fn, const u16* __restrict__ wn,
    const int* __restrict__ labels, float2* __restrict__ ps) {
  __shared__ __align__(16) u16 a_lds[BM * D_SZ];  // 32 KB
  __shared__ __align__(16) u16 b_lds[BN * D_SZ];  // 32 KB

  const int tid  = threadIdx.x;
  const int lane = tid & 63;
  const int wid  = tid >> 6;
  const int wr   = wid >> 1, wc = wid & 1;
  const int cb   = blockIdx.x;          // 0..GRID_C-1
  const int r0   = blockIdx.y * BM;     // row tile base
  const int hi   = lane >> 4;
  const int l15  = lane & 15;

  // ---- stage A once (swizzled source -> linear LDS; XOR involution) ----
  #pragma unroll
  for (int it = 0; it < 8; ++it) {
    int idx  = it * 256 + tid;          // 16B chunk id
    int r    = idx >> 4;
    int k16  = (idx & 15) ^ (r & 7);    // pre-swizzled source slot
    int wbase = it * 256 + (tid & ~63); // wave-uniform LDS base chunk
    gload_lds16(fn + (size_t)(r0 + r) * D_SZ + k16 * 8, &a_lds[wbase * 8]);
  }
  asm volatile("s_waitcnt vmcnt(0)" ::: "memory");
  __syncthreads();

  // ---- A fragments held in registers for the whole kernel ----
  bf16x8 afrag[4][4];
  #pragma unroll
  for (int i = 0; i < 4; ++i) {
    int row = wr * 64 + i * 16 + l15;
    #pragma unroll
    for (int kk = 0; kk < 4; ++kk) {
      int o16 = (kk * 4 + hi) ^ (row & 7);      // swizzled read
      afrag[i][kk] = *(const bf16x8*)&a_lds[row * D_SZ + o16 * 8];
    }
  }
  // labels of this lane's 16 output rows
  int labreg[4][4];
  #pragma unroll
  for (int i = 0; i < 4; ++i)
    #pragma unroll
    for (int r = 0; r < 4; ++r)
      labreg[i][r] = labels[r0 + wr * 64 + i * 16 + hi * 4 + r];

  float sacc[4][4] = {};
  float suma[4][4] = {};

  for (int sub = 0; sub < NSUB; ++sub) {
    int c0 = cb * CPB + sub * BN;
    if (c0 >= C_SZ) break;              // block-uniform

    // ---- stage B sub-tile ----
    #pragma unroll
    for (int it = 0; it < 8; ++it) {
      int idx = it * 256 + tid;
      int cl  = idx >> 4;
      int k16 = (idx & 15) ^ (cl & 7);
      int cg  = c0 + cl; if (cg > C_SZ - 1) cg = C_SZ - 1;   // clamp OOB
      int wbase = it * 256 + (tid & ~63);
      gload_lds16(wn + (size_t)cg * D_SZ + k16 * 8, &b_lds[wbase * 8]);
    }
    asm volatile("s_waitcnt vmcnt(0)" ::: "memory");
    __syncthreads();

    f32x4 acc[4][4] = {};
    #pragma unroll
    for (int j = 0; j < 4; ++j) {
      bf16x8 bfrag[4];
      int col = wc * 64 + j * 16 + l15;
      #pragma unroll
      for (int kk = 0; kk < 4; ++kk) {
        int o16 = (kk * 4 + hi) ^ (col & 7);
        bfrag[kk] = *(const bf16x8*)&b_lds[col * D_SZ + o16 * 8];
      }
      #pragma unroll
      for (int i = 0; i < 4; ++i)
        #pragma unroll
        for (int kk = 0; kk < 4; ++kk)
          acc[i][j] = __builtin_amdgcn_mfma_f32_16x16x32_bf16(
              afrag[i][kk], bfrag[kk], acc[i][j], 0, 0, 0);
    }

    // ---- epilogue: clip, scale, margin, exp(z-30), accumulate ----
    #pragma unroll
    for (int j = 0; j < 4; ++j) {
      int colg = c0 + wc * 64 + j * 16 + l15;
      bool valid = colg < C_SZ;
      #pragma unroll
      for (int i = 0; i < 4; ++i) {
        #pragma unroll
        for (int r = 0; r < 4; ++r) {
          float cos = acc[i][j][r];
          cos = fminf(1.0f, fmaxf(-1.0f, cos));
          float z = S_SC * cos;
          if (colg == labreg[i][r]) z -= SM_;
          float e = exp2f(z * 1.44269504f - 43.2808512f);  // exp(z-30)
          if (valid) { sacc[i][r] += e; suma[i][r] += z; }
        }
      }
    }
    __syncthreads();   // before next sub-tile overwrites b_lds
  }

  // ---- reduce across the 16 lanes sharing each row, write partials ----
  #pragma unroll
  for (int i = 0; i < 4; ++i)
    #pragma unroll
    for (int r = 0; r < 4; ++r) {
      float s = sacc[i][r], u = suma[i][r];
      #pragma unroll
      for (int m = 1; m < 16; m <<= 1) {
        s += __shfl_xor(s, m, 64);
        u += __shfl_xor(u, m, 64);
      }
      if (l15 == 0) {
        int rowg = r0 + wr * 64 + i * 16 + hi * 4 + r;
        ps[(size_t)rowg * NSLOT + cb * 2 + wc] = make_float2(s, u);
      }
    }
}

// ---------------- merge partials -> per-row loss ----------------
__global__ void merge_kernel(const float2* __restrict__ ps,
                             const float* __restrict__ cosy,
                             float* __restrict__ losses) {
  int row  = (blockIdx.x * blockDim.x + threadIdx.x) >> 6;
  int lane = threadIdx.x & 63;
  if (row >= B_SZ) return;
  float s = 0.0f, u = 0.0f;
  for (int k = lane; k < NSLOT; k += 64) {
    float2 p = ps[(size_t)row * NSLOT + k];
    s += p.x; u += p.y;
  }
  #pragma unroll
  for (int m = 1; m < 64; m <<= 1) {
    s += __shfl_xor(s, m, 64);
    u += __shfl_xor(u, m, 64);
  }
  if (lane == 0) {
    float lse = 30.0f + logf(s);
    float zy  = S_SC * (cosy[row] - 0.3f);
    losses[row] = lse - (1.0f - EPS_) * zy - (EPS_ / (float)C_SZ) * u;
  }
}

// ---------------- deterministic mean over B ----------------
__global__ void final_kernel(const float* __restrict__ losses, float* __restrict__ out) {
  __shared__ float red[256];
  int tid = threadIdx.x;
  float s = 0.0f;
  for (int k = tid; k < B_SZ; k += 256) s += losses[k];
  red[tid] = s;
  __syncthreads();
  for (int off = 128; off > 0; off >>= 1) {
    if (tid < off) red[tid] += red[tid + off];
    __syncthreads();
  }
  if (tid == 0) out[0] = red[0] / (float)B_SZ;
}

extern "C" void kernel_launch(void* const* d_in, const int* in_sizes, int n_in,
                              void* d_out, int out_size, void* d_ws, size_t ws_size,
                              hipStream_t stream) {
  const float* feat   = (const float*)d_in[0];
  const int*   labels = (const int*)d_in[1];
  const float* weight = (const float*)d_in[2];
  float* out = (float*)d_out;

  char* ws = (char*)d_ws;
  size_t off = 0;
  u16* wn = (u16*)(ws + off);        off += (size_t)C_SZ * D_SZ * 2;  // 25.6 MB
  off = (off + 255) & ~(size_t)255;
  u16* fn = (u16*)(ws + off);        off += (size_t)B_SZ * D_SZ * 2;  // 0.5 MB
  off = (off + 255) & ~(size_t)255;
  float* cosy = (float*)(ws + off);  off += (size_t)B_SZ * 4;
  off = (off + 255) & ~(size_t)255;
  float2* ps = (float2*)(ws + off);  off += (size_t)B_SZ * NSLOT * 8; // 3.2 MB
  off = (off + 255) & ~(size_t)255;
  float* losses = (float*)(ws + off);

  rownorm_bf16_kernel<<<(C_SZ + 3) / 4, 256, 0, stream>>>(weight, wn, C_SZ);
  rownorm_bf16_kernel<<<(B_SZ + 3) / 4, 256, 0, stream>>>(feat, fn, B_SZ);
  labeldot_kernel<<<(B_SZ + 3) / 4, 256, 0, stream>>>(feat, labels, weight, cosy);

  dim3 grid(GRID_C, B_SZ / BM);
  gemm_partial_kernel<<<grid, 256, 0, stream>>>(fn, wn, labels, ps);

  merge_kernel<<<(B_SZ + 3) / 4, 256, 0, stream>>>(ps, cosy, losses);
  final_kernel<<<1, 256, 0, stream>>>(losses, out);
}

// Round 2
// 107.249 us; speedup vs baseline: 2.1547x; 2.1547x over previous
//
#include <hip/hip_runtime.h>
#include <stdint.h>
#include <math.h>

#define B_SZ   2048
#define D_SZ   128
#define C_SZ   100000
#define S_SC   30.0f
#define EPS_   0.1f

// GEMM tiling
#define BM     128
#define BN     128
#define NSUB   8
#define CPB    (BN*NSUB)                  // 1024 cols per block
#define GRID_C ((C_SZ + CPB - 1)/CPB)     // 98
#define C_PAD  (GRID_C*CPB)               // 100352 (pad rows of wn zeroed)
#define NSLOT  (GRID_C*2)                 // 196 partial slots per row
#define PAD_S  3.293883e-11f              // 352 * exp(-30), subtracted in merge
#define L2E30  43.2808512f                // 30*log2(e)

typedef float  f32x4  __attribute__((ext_vector_type(4)));
typedef short  bf16x8 __attribute__((ext_vector_type(8)));
typedef unsigned short u16;

__device__ __forceinline__ void gload_lds16(const void* g, void* l) {
  __builtin_amdgcn_global_load_lds(
      (const __attribute__((address_space(1))) void*)g,
      (__attribute__((address_space(3))) void*)l, 16, 0, 0);
}

__device__ __forceinline__ u16 f2bf(float f) {
  unsigned u = __float_as_uint(f);
  u += 0x7fffu + ((u >> 16) & 1u);   // round-to-nearest-even
  return (u16)(u >> 16);
}

// ---------------- row L2-normalize -> bf16 (one wave per row) ----------------
// rows >= valid_rows are written as zeros (padding for the GEMM C-dimension).
__global__ void rownorm_bf16_kernel(const float* __restrict__ in,
                                    u16* __restrict__ out, int rows, int valid_rows) {
  int row  = (blockIdx.x * blockDim.x + threadIdx.x) >> 6;
  int lane = threadIdx.x & 63;
  if (row >= rows) return;
  if (row >= valid_rows) {
    ((ushort2*)(out + (size_t)row * D_SZ))[lane] = make_ushort2(0, 0);
    return;
  }
  float2 v = ((const float2*)(in + (size_t)row * D_SZ))[lane];
  float ss = v.x * v.x + v.y * v.y;
  #pragma unroll
  for (int m = 1; m < 64; m <<= 1) ss += __shfl_xor(ss, m, 64);
  float rn = 1.0f / sqrtf(ss);
  ushort2 o;
  o.x = f2bf(v.x * rn);
  o.y = f2bf(v.y * rn);
  ((ushort2*)(out + (size_t)row * D_SZ))[lane] = o;
}

// ---------------- exact fp32 cos at the label position ----------------
__global__ void labeldot_kernel(const float* __restrict__ f,
                                const int* __restrict__ labels,
                                const float* __restrict__ w,
                                float* __restrict__ cosy) {
  int row  = (blockIdx.x * blockDim.x + threadIdx.x) >> 6;
  int lane = threadIdx.x & 63;
  if (row >= B_SZ) return;
  int y = labels[row];
  float2 fv = ((const float2*)(f + (size_t)row * D_SZ))[lane];
  float2 wv = ((const float2*)(w + (size_t)y   * D_SZ))[lane];
  float d  = fv.x * wv.x + fv.y * wv.y;
  float ff = fv.x * fv.x + fv.y * fv.y;
  float ww = wv.x * wv.x + wv.y * wv.y;
  #pragma unroll
  for (int m = 1; m < 64; m <<= 1) {
    d  += __shfl_xor(d,  m, 64);
    ff += __shfl_xor(ff, m, 64);
    ww += __shfl_xor(ww, m, 64);
  }
  if (lane == 0) {
    float c = d / (sqrtf(ff) * sqrtf(ww));
    c = fminf(1.0f, fmaxf(-1.0f, c));
    cosy[row] = c;
  }
}

// ---------------- fused bf16 MFMA GEMM + softmax partials ----------------
// block: 256 thr (4 waves, 2x2). Rows blockIdx.x*128..+127, cols blockIdx.y*1024..+1023.
// Partials per row per block-half: s = sum exp(30*cos-30), u = sum cos.
// No margin, no clip here (fixed up in merge from fp32 cosy).
__global__ __launch_bounds__(256, 2) void gemm_partial_kernel(
    const u16* __restrict__ fn, const u16* __restrict__ wn,
    float2* __restrict__ ps) {
  // lds[0] stages A first (A then lives in registers), then B subtiles
  // ping-pong: B(s) lives in lds[(s+1)&1].
  __shared__ __align__(16) u16 lds[2][BN * D_SZ];  // 2 x 32 KB

  const int tid  = threadIdx.x;
  const int lane = tid & 63;
  const int wid  = tid >> 6;
  const int wr   = wid >> 1, wc = wid & 1;
  const int cb   = blockIdx.y;          // 0..GRID_C-1
  const int r0   = blockIdx.x * BM;     // row tile base
  const int hi   = lane >> 4;
  const int l15  = lane & 15;

  // ---- prologue: stage A -> lds[0], B(0) -> lds[1] ----
  #pragma unroll
  for (int it = 0; it < 8; ++it) {
    int idx  = it * 256 + tid;          // 16B chunk id
    int r    = idx >> 4;
    int k16  = (idx & 15) ^ (r & 7);    // pre-swizzled source slot
    int wbase = it * 256 + (tid & ~63); // wave-uniform LDS base chunk
    gload_lds16(fn + (size_t)(r0 + r) * D_SZ + k16 * 8, &lds[0][wbase * 8]);
  }
  {
    int c0 = cb * CPB;                  // B(0)
    #pragma unroll
    for (int it = 0; it < 8; ++it) {
      int idx = it * 256 + tid;
      int cl  = idx >> 4;
      int k16 = (idx & 15) ^ (cl & 7);
      int wbase = it * 256 + (tid & ~63);
      gload_lds16(wn + (size_t)(c0 + cl) * D_SZ + k16 * 8, &lds[1][wbase * 8]);
    }
  }
  asm volatile("s_waitcnt vmcnt(8)" ::: "memory");   // A arrived; B(0) in flight
  __builtin_amdgcn_s_barrier();

  // ---- A fragments held in registers for the whole kernel ----
  bf16x8 afrag[4][4];
  #pragma unroll
  for (int i = 0; i < 4; ++i) {
    int row = wr * 64 + i * 16 + l15;
    #pragma unroll
    for (int kk = 0; kk < 4; ++kk) {
      int o16 = (kk * 4 + hi) ^ (row & 7);      // swizzled read
      afrag[i][kk] = *(const bf16x8*)&lds[0][row * D_SZ + o16 * 8];
    }
  }
  asm volatile("s_waitcnt lgkmcnt(0)" ::: "memory");  // afrag in regs
  __builtin_amdgcn_s_barrier();                       // lds[0] now reusable

  float sacc[4][4] = {};
  float suma[4][4] = {};

  #pragma unroll 1
  for (int sub = 0; sub < NSUB; ++sub) {
    // ---- prefetch B(sub+1) into the buffer not being computed from ----
    if (sub < NSUB - 1) {
      int c0n = cb * CPB + (sub + 1) * BN;
      #pragma unroll
      for (int it = 0; it < 8; ++it) {
        int idx = it * 256 + tid;
        int cl  = idx >> 4;
        int k16 = (idx & 15) ^ (cl & 7);
        int wbase = it * 256 + (tid & ~63);
        gload_lds16(wn + (size_t)(c0n + cl) * D_SZ + k16 * 8,
                    &lds[sub & 1][wbase * 8]);
      }
      asm volatile("s_waitcnt vmcnt(8)" ::: "memory");  // B(sub) done, B(sub+1) in flight
    } else {
      asm volatile("s_waitcnt vmcnt(0)" ::: "memory");  // last: drain
    }
    __builtin_amdgcn_s_barrier();

    const u16* bbuf = lds[(sub + 1) & 1];

    f32x4 acc[4][4] = {};
    #pragma unroll
    for (int j = 0; j < 4; ++j) {
      bf16x8 bfrag[4];
      int col = wc * 64 + j * 16 + l15;
      #pragma unroll
      for (int kk = 0; kk < 4; ++kk) {
        int o16 = (kk * 4 + hi) ^ (col & 7);
        bfrag[kk] = *(const bf16x8*)&bbuf[col * D_SZ + o16 * 8];
      }
      #pragma unroll
      for (int i = 0; i < 4; ++i)
        #pragma unroll
        for (int kk = 0; kk < 4; ++kk)
          acc[i][j] = __builtin_amdgcn_mfma_f32_16x16x32_bf16(
              afrag[i][kk], bfrag[kk], acc[i][j], 0, 0, 0);
    }

    // ---- epilogue: e = exp(30*cos - 30), s += e, u += cos ----
    #pragma unroll
    for (int j = 0; j < 4; ++j) {
      #pragma unroll
      for (int i = 0; i < 4; ++i) {
        f32x4 a4 = acc[i][j];
        #pragma unroll
        for (int r = 0; r < 4; ++r) {
          float e = __builtin_amdgcn_exp2f(a4[r] * L2E30 - L2E30);
          sacc[i][r] += e;
          suma[i][r] += a4[r];
        }
      }
    }

    asm volatile("s_waitcnt lgkmcnt(0)" ::: "memory");  // bfrag reads drained
    __builtin_amdgcn_s_barrier();   // all waves done with bbuf before overwrite
  }

  // ---- reduce across the 16 lanes sharing each row, write partials ----
  #pragma unroll
  for (int i = 0; i < 4; ++i)
    #pragma unroll
    for (int r = 0; r < 4; ++r) {
      float s = sacc[i][r], u = suma[i][r];
      #pragma unroll
      for (int m = 1; m < 16; m <<= 1) {
        s += __shfl_xor(s, m, 64);
        u += __shfl_xor(u, m, 64);
      }
      if (l15 == 0) {
        int rowg = r0 + wr * 64 + i * 16 + hi * 4 + r;
        ps[(size_t)rowg * NSLOT + cb * 2 + wc] = make_float2(s, u);
      }
    }
}

// ---------------- merge partials -> per-row loss ----------------
// Fixes: pad columns (exact), label margin (from fp32 cosy).
__global__ void merge_kernel(const float2* __restrict__ ps,
                             const float* __restrict__ cosy,
                             float* __restrict__ losses) {
  int row  = (blockIdx.x * blockDim.x + threadIdx.x) >> 6;
  int lane = threadIdx.x & 63;
  if (row >= B_SZ) return;
  float s = 0.0f, u = 0.0f;
  for (int k = lane; k < NSLOT; k += 64) {
    float2 p = ps[(size_t)row * NSLOT + k];
    s += p.x; u += p.y;
  }
  #pragma unroll
  for (int m = 1; m < 64; m <<= 1) {
    s += __shfl_xor(s, m, 64);
    u += __shfl_xor(u, m, 64);
  }
  if (lane == 0) {
    float zy = S_SC * cosy[row];                  // fp32 label logit (no margin)
    s = s - PAD_S + expf(zy - 39.0f) - expf(zy - 30.0f);  // margin swap at label
    s = fmaxf(s, 1e-30f);
    float lse = 30.0f + logf(s);
    float sum_z = S_SC * u - 9.0f;                // margin included
    losses[row] = lse - 0.9f * (zy - 9.0f) - 1e-6f * sum_z;
  }
}

// ---------------- deterministic mean over B ----------------
__global__ void final_kernel(const float* __restrict__ losses, float* __restrict__ out) {
  __shared__ float red[256];
  int tid = threadIdx.x;
  float s = 0.0f;
  for (int k = tid; k < B_SZ; k += 256) s += losses[k];
  red[tid] = s;
  __syncthreads();
  for (int off = 128; off > 0; off >>= 1) {
    if (tid < off) red[tid] += red[tid + off];
    __syncthreads();
  }
  if (tid == 0) out[0] = red[0] / (float)B_SZ;
}

extern "C" void kernel_launch(void* const* d_in, const int* in_sizes, int n_in,
                              void* d_out, int out_size, void* d_ws, size_t ws_size,
                              hipStream_t stream) {
  const float* feat   = (const float*)d_in[0];
  const int*   labels = (const int*)d_in[1];
  const float* weight = (const float*)d_in[2];
  float* out = (float*)d_out;

  char* ws = (char*)d_ws;
  size_t off = 0;
  u16* wn = (u16*)(ws + off);        off += (size_t)C_PAD * D_SZ * 2;  // 25.7 MB
  off = (off + 255) & ~(size_t)255;
  u16* fn = (u16*)(ws + off);        off += (size_t)B_SZ * D_SZ * 2;   // 0.5 MB
  off = (off + 255) & ~(size_t)255;
  float* cosy = (float*)(ws + off);  off += (size_t)B_SZ * 4;
  off = (off + 255) & ~(size_t)255;
  float2* ps = (float2*)(ws + off);  off += (size_t)B_SZ * NSLOT * 8;  // 3.2 MB
  off = (off + 255) & ~(size_t)255;
  float* losses = (float*)(ws + off);

  rownorm_bf16_kernel<<<(C_PAD + 3) / 4, 256, 0, stream>>>(weight, wn, C_PAD, C_SZ);
  rownorm_bf16_kernel<<<(B_SZ + 3) / 4, 256, 0, stream>>>(feat, fn, B_SZ, B_SZ);
  labeldot_kernel<<<(B_SZ + 3) / 4, 256, 0, stream>>>(feat, labels, weight, cosy);

  dim3 grid(B_SZ / BM, GRID_C);   // x = row tiles (16), y = col tiles (98)
  gemm_partial_kernel<<<grid, 256, 0, stream>>>(fn, wn, ps);

  merge_kernel<<<(B_SZ + 3) / 4, 256, 0, stream>>>(ps, cosy, losses);
  final_kernel<<<1, 256, 0, stream>>>(losses, out);
}